// Round 3
// baseline (319.359 us; speedup 1.0000x reference)
//
#include <hip/hip_runtime.h>

// Problem constants: VOCAB=100000, EMB=300, B=2048, L=200, H=128, OUT=20
#define BB   2048
#define LL   200
#define EMB  300
#define HH   128
#define OUTD 20
#define UNR  5      // gather rows in flight per wave

// One block per sample, 256 threads = 4 waves.
// Phase 1 (gather): wave w owns 50 contiguous rows [w*50, w*50+50).
//   Software-pipelined: issue UNR rows of float4 loads into separate regs,
//   THEN accumulate — keeps UNR*1.2KB per wave in flight to hide gather latency.
// Phase 2: cross-wave reduce in LDS, split-k W1 GEMV, tiny W2 GEMV.
__global__ __launch_bounds__(256) void fused_dnn(
    const int*   __restrict__ x,        // [B, L]
    const int*   __restrict__ lengths,  // [B]
    const float* __restrict__ table,    // [VOCAB, EMB]
    const float* __restrict__ W1,       // [EMB, H]
    const float* __restrict__ b1,       // [H]
    const float* __restrict__ W2,       // [H, OUT]
    const float* __restrict__ b2,       // [OUT]
    float*       __restrict__ out)      // [B, OUT]
{
    __shared__ int    idx_s[LL];
    __shared__ float4 part_s[4][76];
    __shared__ float  rep_s[EMB];
    __shared__ float  h_part[2][HH];
    __shared__ float  h_s[HH];

    const int b    = blockIdx.x;
    const int t    = threadIdx.x;
    const int w    = t >> 6;            // wave 0..3
    const int lane = t & 63;

    if (t < LL) idx_s[t] = x[b * LL + t];
    __syncthreads();

    float4 acc_a = make_float4(0.f, 0.f, 0.f, 0.f);
    float4 acc_b = make_float4(0.f, 0.f, 0.f, 0.f);
    const bool hasb = (lane < (EMB / 4 - 64));   // lane < 11

    const int base = w * (LL / 4);               // 50 rows per wave
    for (int i = 0; i < LL / 4; i += UNR) {
        const float4* rowp[UNR];
        #pragma unroll
        for (int u = 0; u < UNR; ++u)
            rowp[u] = (const float4*)(table + (size_t)idx_s[base + i + u] * EMB);

        float4 va[UNR];
        float4 vb[UNR];
        #pragma unroll
        for (int u = 0; u < UNR; ++u) {
            va[u] = rowp[u][lane];
            if (hasb) vb[u] = rowp[u][64 + lane];
        }
        #pragma unroll
        for (int u = 0; u < UNR; ++u) {
            acc_a.x += va[u].x; acc_a.y += va[u].y;
            acc_a.z += va[u].z; acc_a.w += va[u].w;
            if (hasb) {
                acc_b.x += vb[u].x; acc_b.y += vb[u].y;
                acc_b.z += vb[u].z; acc_b.w += vb[u].w;
            }
        }
    }

    part_s[w][lane] = acc_a;
    if (hasb) part_s[w][64 + lane] = acc_b;
    __syncthreads();

    // cross-wave reduce + scale
    const float inv_len = 1.0f / (float)lengths[b];
    const float* ps = (const float*)part_s;      // [4][304] floats
    {
        float s = ps[t] + ps[304 + t] + ps[608 + t] + ps[912 + t];
        rep_s[t] = s * inv_len;
    }
    if (t < (EMB - 256)) {
        int c = 256 + t;
        float s = ps[c] + ps[304 + c] + ps[608 + c] + ps[912 + c];
        rep_s[c] = s * inv_len;
    }
    __syncthreads();

    // h = relu(rep @ W1 + b1), split-k across the two half-blocks
    {
        const int half = t >> 7;
        const int col  = t & 127;
        float hacc = (half == 0) ? b1[col] : 0.0f;
        const int k0 = half * (EMB / 2);
        #pragma unroll 5
        for (int k = k0; k < k0 + EMB / 2; ++k)
            hacc = fmaf(rep_s[k], W1[k * HH + col], hacc);
        h_part[half][col] = hacc;
    }
    __syncthreads();
    if (t < HH)
        h_s[t] = fmaxf(h_part[0][t] + h_part[1][t], 0.0f);
    __syncthreads();

    // logits = h @ W2 + b2
    if (t < OUTD) {
        float oacc = b2[t];
        #pragma unroll
        for (int k = 0; k < HH; ++k)
            oacc = fmaf(h_s[k], W2[k * OUTD + t], oacc);
        out[b * OUTD + t] = oacc;
    }
}

extern "C" void kernel_launch(void* const* d_in, const int* in_sizes, int n_in,
                              void* d_out, int out_size, void* d_ws, size_t ws_size,
                              hipStream_t stream) {
    const int*   x       = (const int*)  d_in[0];
    const int*   lengths = (const int*)  d_in[1];
    const float* table   = (const float*)d_in[2];
    const float* W1      = (const float*)d_in[3];
    const float* b1      = (const float*)d_in[4];
    const float* W2      = (const float*)d_in[5];
    const float* b2      = (const float*)d_in[6];
    float*       out     = (float*)d_out;

    fused_dnn<<<BB, 256, 0, stream>>>(x, lengths, table, W1, b1, W2, b2, out);
}

// Round 4
// 241.687 us; speedup vs baseline: 1.3214x; 1.3214x over previous
//
#include <hip/hip_runtime.h>

// Problem constants: VOCAB=100000, EMB=300, B=2048, L=200, H=128, OUT=20
#define BB   2048
#define LL   200
#define EMB  300
#define HH   128
#define OUTD 20
#define NSRT 256    // bitonic sort width (LL padded with INT_MAX)

// One block per sample, 256 threads = 4 waves.
// Phase 0: bitonic-sort the 200 indices ascending in LDS. All 2048 blocks are
//   co-resident (8 blocks/CU x 256 CU), so sorted-order gathers make every
//   block sweep the vocab range in lockstep -> the active band (~10-20 MB)
//   stays hot in L3/L2, cutting HBM fetch toward the 120 MB compulsory min.
// Phase 1: gather-sum, rows interleaved across waves (l = w + 4*i) to keep
//   all 4 waves in the same index band. float4 loads, 16 B/lane.
// Phase 2: cross-wave reduce in LDS, split-k W1 GEMV, tiny W2 GEMV.
__global__ __launch_bounds__(256) void fused_dnn(
    const int*   __restrict__ x,        // [B, L]
    const int*   __restrict__ lengths,  // [B]
    const float* __restrict__ table,    // [VOCAB, EMB]
    const float* __restrict__ W1,       // [EMB, H]
    const float* __restrict__ b1,       // [H]
    const float* __restrict__ W2,       // [H, OUT]
    const float* __restrict__ b2,       // [OUT]
    float*       __restrict__ out)      // [B, OUT]
{
    __shared__ int    idx_s[NSRT];
    __shared__ float4 part_s[4][76];
    __shared__ float  rep_s[EMB];
    __shared__ float  h_part[2][HH];
    __shared__ float  h_s[HH];

    const int b    = blockIdx.x;
    const int t    = threadIdx.x;
    const int w    = t >> 6;            // wave 0..3
    const int lane = t & 63;

    idx_s[t] = (t < LL) ? x[b * LL + t] : 0x7FFFFFFF;
    __syncthreads();

    // ---- bitonic sort ascending over NSRT=256 elements, thread t owns slot t
    #pragma unroll
    for (int k = 2; k <= NSRT; k <<= 1) {
        #pragma unroll
        for (int j = k >> 1; j > 0; j >>= 1) {
            const int ixj = t ^ j;
            if (ixj > t) {
                const int a0 = idx_s[t];
                const int a1 = idx_s[ixj];
                const bool up = ((t & k) == 0);      // ascending segment?
                if ((a0 > a1) == up) { idx_s[t] = a1; idx_s[ixj] = a0; }
            }
            __syncthreads();
        }
    }

    // ---- gather-sum in sorted order; waves interleaved to share the band
    float4 acc_a = make_float4(0.f, 0.f, 0.f, 0.f);
    float4 acc_b = make_float4(0.f, 0.f, 0.f, 0.f);
    const bool hasb = (lane < (EMB / 4 - 64));   // lane < 11

    #pragma unroll 2
    for (int l = w; l < LL; l += 4) {
        const float4* row = (const float4*)(table + (size_t)idx_s[l] * EMB);
        float4 va = row[lane];
        acc_a.x += va.x; acc_a.y += va.y; acc_a.z += va.z; acc_a.w += va.w;
        if (hasb) {
            float4 vb = row[64 + lane];
            acc_b.x += vb.x; acc_b.y += vb.y; acc_b.z += vb.z; acc_b.w += vb.w;
        }
    }

    part_s[w][lane] = acc_a;
    if (hasb) part_s[w][64 + lane] = acc_b;
    __syncthreads();

    // ---- cross-wave reduce + scale
    const float inv_len = 1.0f / (float)lengths[b];
    const float* ps = (const float*)part_s;      // [4][304] floats
    {
        float s = ps[t] + ps[304 + t] + ps[608 + t] + ps[912 + t];
        rep_s[t] = s * inv_len;
    }
    if (t < (EMB - 256)) {
        int c = 256 + t;
        float s = ps[c] + ps[304 + c] + ps[608 + c] + ps[912 + c];
        rep_s[c] = s * inv_len;
    }
    __syncthreads();

    // ---- h = relu(rep @ W1 + b1), split-k across the two half-blocks
    {
        const int half = t >> 7;
        const int col  = t & 127;
        float hacc = (half == 0) ? b1[col] : 0.0f;
        const int k0 = half * (EMB / 2);
        #pragma unroll 5
        for (int k = k0; k < k0 + EMB / 2; ++k)
            hacc = fmaf(rep_s[k], W1[k * HH + col], hacc);
        h_part[half][col] = hacc;
    }
    __syncthreads();
    if (t < HH)
        h_s[t] = fmaxf(h_part[0][t] + h_part[1][t], 0.0f);
    __syncthreads();

    // ---- logits = h @ W2 + b2
    if (t < OUTD) {
        float oacc = b2[t];
        #pragma unroll
        for (int k = 0; k < HH; ++k)
            oacc = fmaf(h_s[k], W2[k * OUTD + t], oacc);
        out[b * OUTD + t] = oacc;
    }
}

extern "C" void kernel_launch(void* const* d_in, const int* in_sizes, int n_in,
                              void* d_out, int out_size, void* d_ws, size_t ws_size,
                              hipStream_t stream) {
    const int*   x       = (const int*)  d_in[0];
    const int*   lengths = (const int*)  d_in[1];
    const float* table   = (const float*)d_in[2];
    const float* W1      = (const float*)d_in[3];
    const float* b1      = (const float*)d_in[4];
    const float* W2      = (const float*)d_in[5];
    const float* b2      = (const float*)d_in[6];
    float*       out     = (float*)d_out;

    fused_dnn<<<BB, 256, 0, stream>>>(x, lengths, table, W1, b1, W2, b2, out);
}

// Round 5
// 241.619 us; speedup vs baseline: 1.3217x; 1.0003x over previous
//
#include <hip/hip_runtime.h>

// Problem constants: VOCAB=100000, EMB=300, B=2048, L=200, H=128, OUT=20
#define BB   2048
#define LL   200
#define EMB  300
#define HH   128
#define OUTD 20
#define NSRT 256        // bitonic sort width (LL padded with INT_MAX)
#define RPW  (LL / 4)   // 50 rows per wave

// One block per sample, 256 threads = 4 waves.
// Phase 0: bitonic-sort the 200 indices ascending in LDS (cheap; keeps all
//   co-resident blocks sweeping the vocab in the same direction -> better L3).
// Phase 1: gather-sum. Lane j of wave w holds the wave's j-th (sorted,
//   wave-interleaved) row index in a REGISTER; readlane(i) makes each row's
//   base address SGPR-resident, so an in-flight row costs only ~5 data VGPRs
//   (global_load_dwordx4 v, v_off, s[base]). #pragma unroll 5 keeps ~5+ rows
//   in flight per wave at <=64 VGPR (8 waves/SIMD) — deep memory pipeline
//   without R3's VGPR explosion.
// Phase 2: cross-wave reduce in LDS, split-k W1 GEMV, tiny W2 GEMV.
__global__ __launch_bounds__(256) void fused_dnn(
    const int*   __restrict__ x,        // [B, L]
    const int*   __restrict__ lengths,  // [B]
    const float* __restrict__ table,    // [VOCAB, EMB]
    const float* __restrict__ W1,       // [EMB, H]
    const float* __restrict__ b1,       // [H]
    const float* __restrict__ W2,       // [H, OUT]
    const float* __restrict__ b2,       // [OUT]
    float*       __restrict__ out)      // [B, OUT]
{
    __shared__ int    idx_s[NSRT];
    __shared__ float4 part_s[4][76];
    __shared__ float  rep_s[EMB];
    __shared__ float  h_part[2][HH];
    __shared__ float  h_s[HH];

    const int b    = blockIdx.x;
    const int t    = threadIdx.x;
    const int w    = t >> 6;            // wave 0..3
    const int lane = t & 63;

    idx_s[t] = (t < LL) ? x[b * LL + t] : 0x7FFFFFFF;
    __syncthreads();

    // ---- bitonic sort ascending over NSRT=256 elements, thread t owns slot t
    #pragma unroll
    for (int k = 2; k <= NSRT; k <<= 1) {
        #pragma unroll
        for (int j = k >> 1; j > 0; j >>= 1) {
            const int ixj = t ^ j;
            if (ixj > t) {
                const int a0 = idx_s[t];
                const int a1 = idx_s[ixj];
                const bool up = ((t & k) == 0);
                if ((a0 > a1) == up) { idx_s[t] = a1; idx_s[ixj] = a0; }
            }
            __syncthreads();
        }
    }

    // lane j holds this wave's j-th row index (rows wave-interleaved over the
    // sorted order so all 4 waves stay in the same vocab band)
    const int myidx = (lane < RPW) ? idx_s[w + 4 * lane] : 0;

    // ---- gather-sum with scalar-base pipelined loads
    float4 acc_a = make_float4(0.f, 0.f, 0.f, 0.f);
    float4 acc_b = make_float4(0.f, 0.f, 0.f, 0.f);
    const bool hasb = (lane < (EMB / 4 - 64));   // lane < 11

    #pragma unroll 5
    for (int i = 0; i < RPW; ++i) {
        const int ridx = __builtin_amdgcn_readlane(myidx, i);   // uniform -> SGPR base
        const float4* row = (const float4*)(table + (size_t)ridx * EMB);
        float4 va = row[lane];
        acc_a.x += va.x; acc_a.y += va.y; acc_a.z += va.z; acc_a.w += va.w;
        if (hasb) {
            float4 vb = row[64 + lane];
            acc_b.x += vb.x; acc_b.y += vb.y; acc_b.z += vb.z; acc_b.w += vb.w;
        }
    }

    part_s[w][lane] = acc_a;
    if (hasb) part_s[w][64 + lane] = acc_b;
    __syncthreads();

    // ---- cross-wave reduce + scale
    const float inv_len = 1.0f / (float)lengths[b];
    const float* ps = (const float*)part_s;      // [4][304] floats
    {
        float s = ps[t] + ps[304 + t] + ps[608 + t] + ps[912 + t];
        rep_s[t] = s * inv_len;
    }
    if (t < (EMB - 256)) {
        int c = 256 + t;
        float s = ps[c] + ps[304 + c] + ps[608 + c] + ps[912 + c];
        rep_s[c] = s * inv_len;
    }
    __syncthreads();

    // ---- h = relu(rep @ W1 + b1), split-k across the two half-blocks
    {
        const int half = t >> 7;
        const int col  = t & 127;
        float hacc = (half == 0) ? b1[col] : 0.0f;
        const int k0 = half * (EMB / 2);
        #pragma unroll 5
        for (int k = k0; k < k0 + EMB / 2; ++k)
            hacc = fmaf(rep_s[k], W1[k * HH + col], hacc);
        h_part[half][col] = hacc;
    }
    __syncthreads();
    if (t < HH)
        h_s[t] = fmaxf(h_part[0][t] + h_part[1][t], 0.0f);
    __syncthreads();

    // ---- logits = h @ W2 + b2
    if (t < OUTD) {
        float oacc = b2[t];
        #pragma unroll
        for (int k = 0; k < HH; ++k)
            oacc = fmaf(h_s[k], W2[k * OUTD + t], oacc);
        out[b * OUTD + t] = oacc;
    }
}

extern "C" void kernel_launch(void* const* d_in, const int* in_sizes, int n_in,
                              void* d_out, int out_size, void* d_ws, size_t ws_size,
                              hipStream_t stream) {
    const int*   x       = (const int*)  d_in[0];
    const int*   lengths = (const int*)  d_in[1];
    const float* table   = (const float*)d_in[2];
    const float* W1      = (const float*)d_in[3];
    const float* b1      = (const float*)d_in[4];
    const float* W2      = (const float*)d_in[5];
    const float* b2      = (const float*)d_in[6];
    float*       out     = (float*)d_out;

    fused_dnn<<<BB, 256, 0, stream>>>(x, lengths, table, W1, b1, W2, b2, out);
}